// Round 10
// baseline (46.956 us; speedup 1.0000x reference)
//
#include <hip/hip_runtime.h>
#include <math.h>

// QConv2d: x (32,4,64,64) f32, params (4,8,16,16) f32 -> out (32,32,32,32) f32
// B=32 C=4 H=W=64, KH=KW=2 stride 2 -> px=py=32, NW=4, DIM=16, D=8, M=32768

#define TAYLOR_N 9

// ---------------- Kernel 1: zero the output (all 1024 blocks) + expm (blocks<32)
// W'[c*8+d][j][i] = expm(SH)[i][j] * (-i)^popc(i)
__global__ __launch_bounds__(256) void prep_kernel(const float* __restrict__ params,
                                                   float2* __restrict__ wp,
                                                   float4* __restrict__ outz) {
    outz[blockIdx.x * 256 + threadIdx.x] = make_float4(0.f, 0.f, 0.f, 0.f);
    if (blockIdx.x >= 32) return;

    __shared__ float2 X[256];
    __shared__ float2 P0[256];
    __shared__ float2 P1[256];
    __shared__ float red[256];
    __shared__ float srow[16];
    __shared__ int ssexp;

    const int bid = blockIdx.x;      // c*8 + d
    const int tid = threadIdx.x;
    const int i = tid >> 4, j = tid & 15;

    const float* pm = params + bid * 256;
    float pij = pm[i * 16 + j];
    float pji = pm[j * 16 + i];
    float ar = pij - pji;   // asym -> real part of SH
    float ai = pij + pji;   // sym  -> imag part of SH
    red[tid] = fabsf(ar) + fabsf(ai);
    __syncthreads();
    if (j == 0) {
        float s = 0.f;
        for (int t = 0; t < 16; ++t) s += red[i * 16 + t];
        srow[i] = s;
    }
    __syncthreads();
    if (tid == 0) {
        float mx = 0.f;
        for (int t = 0; t < 16; ++t) mx = fmaxf(mx, srow[t]);
        int se = 0;
        while (mx > 0.5f && se < 40) { mx *= 0.5f; se++; }
        ssexp = se;
    }
    __syncthreads();
    const int sexp = ssexp;
    const float scale = exp2f((float)(-sexp));
    const float xr = ar * scale, xi = ai * scale;
    X[tid] = make_float2(xr, xi);
    float2 p = make_float2(xr / TAYLOR_N + ((i == j) ? 1.f : 0.f), xi / TAYLOR_N);
    P0[tid] = p;
    __syncthreads();

    float2 Xr[16];
    #pragma unroll
    for (int t = 0; t < 16; ++t) Xr[t] = X[i * 16 + t];

    float2* cur = P0;
    float2* nxt = P1;
    for (int k = TAYLOR_N - 1; k >= 1; --k) {
        float accr = 0.f, acci = 0.f;
        #pragma unroll
        for (int t = 0; t < 16; ++t) {
            float2 a = Xr[t];
            float2 bb = cur[t * 16 + j];
            accr += a.x * bb.x - a.y * bb.y;
            acci += a.x * bb.y + a.y * bb.x;
        }
        float inv = 1.f / (float)k;
        float2 np = make_float2(accr * inv + ((i == j) ? 1.f : 0.f), acci * inv);
        __syncthreads();
        nxt[tid] = np;
        __syncthreads();
        float2* tmp = cur; cur = nxt; nxt = tmp;
    }
    for (int sq = 0; sq < sexp; ++sq) {
        float accr = 0.f, acci = 0.f;
        #pragma unroll
        for (int t = 0; t < 16; ++t) {
            float2 a = cur[i * 16 + t];
            float2 bb = cur[t * 16 + j];
            accr += a.x * bb.x - a.y * bb.y;
            acci += a.x * bb.y + a.y * bb.x;
        }
        __syncthreads();
        nxt[tid] = make_float2(accr, acci);
        __syncthreads();
        float2* tmp = cur; cur = nxt; nxt = tmp;
    }
    float2 e = cur[tid];
    int pc = __popc(i) & 3;
    float2 o;
    if (pc == 0)      o = make_float2( e.x,  e.y);
    else if (pc == 1) o = make_float2( e.y, -e.x);
    else if (pc == 2) o = make_float2(-e.x, -e.y);
    else              o = make_float2(-e.y,  e.x);
    wp[(bid * 16 + j) * 16 + i] = o;
}

// Fast acos: A&S 4.4.45, |abs err| <= 6.8e-5 over [-1,1]
__device__ __forceinline__ float acos_fast(float t) {
    float ax = fabsf(t);
    float p = fmaf(ax, -0.0187293f, 0.0742610f);
    p = fmaf(ax, p, -0.2121144f);
    p = fmaf(ax, p, 1.5707288f);
    float f = sqrtf(1.0f - ax) * p;
    return (t >= 0.f) ? f : (3.14159265358979f - f);
}

// build r[16] for one site from 4 angles (wire0 = MSB of k)
#define BUILD_R(rr, T0, T1, T2, T3) do {                                   \
    float sn0, cs0, sn1, cs1, sn2, cs2, sn3, cs3;                          \
    __sincosf((T0) * 0.5f, &sn0, &cs0);                                    \
    __sincosf((T1) * 0.5f, &sn1, &cs1);                                    \
    __sincosf((T2) * 0.5f, &sn2, &cs2);                                    \
    __sincosf((T3) * 0.5f, &sn3, &cs3);                                    \
    float p00 = cs0 * cs1, p01 = cs0 * sn1, p10 = sn0 * cs1, p11 = sn0 * sn1; \
    float e0 = p00 * cs2, e1 = p00 * sn2, e2 = p01 * cs2, e3 = p01 * sn2;  \
    float e4 = p10 * cs2, e5 = p10 * sn2, e6 = p11 * cs2, e7 = p11 * sn2;  \
    rr[0]  = e0 * cs3; rr[1]  = e0 * sn3; rr[2]  = e1 * cs3; rr[3]  = e1 * sn3; \
    rr[4]  = e2 * cs3; rr[5]  = e2 * sn3; rr[6]  = e3 * cs3; rr[7]  = e3 * sn3; \
    rr[8]  = e4 * cs3; rr[9]  = e4 * sn3; rr[10] = e5 * cs3; rr[11] = e5 * sn3; \
    rr[12] = e6 * cs3; rr[13] = e6 * sn3; rr[14] = e7 * cs3; rr[15] = e7 * sn3; \
} while (0)

#define SITE_FMA(rr, YR, YI)                                               \
    YR = fmaf(wv.x, rr[2 * kk], YR); YI = fmaf(wv.y, rr[2 * kk], YI);      \
    YR = fmaf(wv.z, rr[2 * kk + 1], YR); YI = fmaf(wv.w, rr[2 * kk + 1], YI);

// ---------------- Kernel 2: main compute ------------------------------------
// G=4 sites/thread. grid = 8(d)*2(chalf)*32(b) blocks, 256 threads.
// (d, chalf, b) all from blockIdx -> W' pointer provably uniform -> rows come
// via s_load (scalar cache broadcast: zero VALU cost, zero DS traffic; one
// 128B row feeds 256 FMA-cycles so ~200cyc scalar latency is hidden with 2
// rows in flight). R7/R8 proved this structure fails ONLY via VGPR-60 spill;
// amdgpu_waves_per_eu(2,4) (validated in R9) lets the allocator target the
// actual 2-waves/SIMD occupancy -> ~128+ VGPR, no spill.
// Epilogue (from R9): partials transposed through LDS so the 2-way
// deterministic fp32 atomics hit lane-consecutive dwords (no RMW
// amplification; a+b bitwise == b+a so 2-way atomic is bit-deterministic).
__global__ __launch_bounds__(256)
__attribute__((amdgpu_waves_per_eu(2, 4)))
void qconv_kernel(const float* __restrict__ x,
                  const float2* __restrict__ wp,
                  float* __restrict__ out) {
    __shared__ float olds[4096];          // [w][sp] partial transpose, 16 KB

    const int bidx = blockIdx.x;          // (d*2 + chalf)*32 + b
    const int d = bidx >> 6;              // uniform
    const int chalf = (bidx >> 5) & 1;    // uniform
    const int b = bidx & 31;              // uniform
    const int tid = threadIdx.x;
    const int ix = tid >> 3;              // 0..31
    const int iy0 = (tid & 7) << 2;       // 0,4,..,28 ; sites iy0..iy0+3

    float outsum[4][4];                   // [site][w]
    #pragma unroll
    for (int s = 0; s < 4; ++s)
        #pragma unroll
        for (int w = 0; w < 4; ++w) outsum[s][w] = 0.f;

    #pragma unroll 1
    for (int cc = 0; cc < 2; ++cc) {
        const int c = chalf * 2 + cc;
        const float* xrow = x + (((b << 2) + c) * 64 + 2 * ix) * 64 + 2 * iy0;
        float4 a0 = *(const float4*)(xrow);
        float4 a1 = *(const float4*)(xrow + 4);
        float4 b0 = *(const float4*)(xrow + 64);
        float4 b1 = *(const float4*)(xrow + 68);

        float r0[16], r1[16], r2[16], r3[16];
        BUILD_R(r0, a0.x, a0.y, b0.x, b0.y);
        BUILD_R(r1, a0.z, a0.w, b0.z, b0.w);
        BUILD_R(r2, a1.x, a1.y, b1.x, b1.y);
        BUILD_R(r3, a1.z, a1.w, b1.z, b1.w);

        const float2* __restrict__ wrow = wp + ((c << 3) + d) * 256;  // uniform
        float tq[4][4];
        #pragma unroll
        for (int s = 0; s < 4; ++s)
            #pragma unroll
            for (int w = 0; w < 4; ++w) tq[s][w] = 0.f;

        #pragma unroll
        for (int jj = 0; jj < 16; ++jj) {
            const float4* wr4 = (const float4*)(wrow + jj * 16);
            float yr0 = 0.f, yi0 = 0.f, yr1 = 0.f, yi1 = 0.f;
            float yr2 = 0.f, yi2 = 0.f, yr3 = 0.f, yi3 = 0.f;
            #pragma unroll
            for (int kk = 0; kk < 8; ++kk) {
                float4 wv = wr4[kk];      // uniform addr -> s_load, CSE'd x4 sites
                SITE_FMA(r0, yr0, yi0)
                SITE_FMA(r1, yr1, yi1)
                SITE_FMA(r2, yr2, yi2)
                SITE_FMA(r3, yr3, yi3)
            }
            float q0 = fmaf(yr0, yr0, yi0 * yi0);
            float q1 = fmaf(yr1, yr1, yi1 * yi1);
            float q2 = fmaf(yr2, yr2, yi2 * yi2);
            float q3 = fmaf(yr3, yr3, yi3 * yi3);
            // w uses bit (3-w) of jj: add if 0, sub if 1 (compile-time signs)
            #pragma unroll
            for (int w = 0; w < 4; ++w) {
                if ((jj >> (3 - w)) & 1) {
                    tq[0][w] -= q0; tq[1][w] -= q1; tq[2][w] -= q2; tq[3][w] -= q3;
                } else {
                    tq[0][w] += q0; tq[1][w] += q1; tq[2][w] += q2; tq[3][w] += q3;
                }
            }
        }

        #pragma unroll
        for (int s = 0; s < 4; ++s)
            #pragma unroll
            for (int w = 0; w < 4; ++w)
                outsum[s][w] += acos_fast(fminf(fmaxf(tq[s][w], -1.f), 1.f));
    }

    // transpose partials through LDS: thread's flat site index = 4*tid + s
    #pragma unroll
    for (int w = 0; w < 4; ++w)
        ((float4*)olds)[w * 256 + tid] =
            make_float4(outsum[0][w], outsum[1][w], outsum[2][w], outsum[3][w]);
    __syncthreads();

    // coalesced 2-way deterministic atomics: lane-consecutive dwords
    float* obase = out + ((b * 32) + (d << 2)) * 1024;
    #pragma unroll
    for (int i = 0; i < 16; ++i)
        unsafeAtomicAdd(obase + i * 256 + tid, olds[i * 256 + tid]);
}

extern "C" void kernel_launch(void* const* d_in, const int* in_sizes, int n_in,
                              void* d_out, int out_size, void* d_ws, size_t ws_size,
                              hipStream_t stream) {
    const float* x = (const float*)d_in[0];
    const float* params = (const float*)d_in[1];
    float* out = (float*)d_out;
    float2* wp = (float2*)d_ws;   // 32 * 256 * 8 bytes = 64 KiB

    prep_kernel<<<1024, 256, 0, stream>>>(params, wp, (float4*)out);
    qconv_kernel<<<8 * 2 * 32, 256, 0, stream>>>(x, wp, out);
}